// Round 1
// baseline (362.119 us; speedup 1.0000x reference)
//
#include <hip/hip_runtime.h>

#define THREADS 256

// feat layout: x_s[0..10) | x_t[10..15) | edge_attr[15..25) | u[25..35)
// d_in = 35, F_OUT = 5

__global__ __launch_bounds__(THREADS) void edge_model_kernel(
    const float* __restrict__ x_s,      // [N_S,10]
    const float* __restrict__ x_t,      // [N_T,5]
    const int* __restrict__ edge_index, // [2,E] row-major: src then tgt
    const float* __restrict__ edge_attr,// [E,10]
    const float* __restrict__ u,        // [64,10]
    const int* __restrict__ batch_e,    // [E]
    const float* __restrict__ W1,       // [35,5]
    const float* __restrict__ b1,       // [5]
    const float* __restrict__ W2,       // [5,5]
    const float* __restrict__ b2,       // [5]
    float* __restrict__ out,            // [E,5]
    int E)
{
    __shared__ float sW1[35 * 5];
    __shared__ float sb1[5];
    __shared__ float sW2[5 * 5];
    __shared__ float sb2[5];
    __shared__ float su[64 * 11];          // stride 11: coprime with 32 banks
    __shared__ float sout[THREADS * 5];    // staging for coalesced store

    const int t = threadIdx.x;

    // --- stage weights + u into LDS (uniform broadcast reads later) ---
    for (int i = t; i < 35 * 5; i += THREADS) sW1[i] = W1[i];
    if (t < 5)  sb1[t] = b1[t];
    if (t < 25) sW2[t] = W2[t];
    if (t >= 32 && t < 37) sb2[t - 32] = b2[t - 32];
    for (int i = t; i < 64 * 10; i += THREADS) {
        int r = i / 10, c = i - r * 10;
        su[r * 11 + c] = u[i];
    }
    __syncthreads();

    const int e = blockIdx.x * THREADS + t;

    if (e < E) {
        const int src = edge_index[e];
        const int tgt = edge_index[E + e];
        const int b   = batch_e[e];

        float feat[35];

        // x_s row: 40 B, 8B-aligned -> float2 x5
        const float2* xs2 = reinterpret_cast<const float2*>(x_s + (size_t)src * 10);
        #pragma unroll
        for (int i = 0; i < 5; ++i) {
            float2 v = xs2[i];
            feat[2 * i]     = v.x;
            feat[2 * i + 1] = v.y;
        }
        // x_t row: 20 B, 4B-aligned -> scalar x5
        #pragma unroll
        for (int i = 0; i < 5; ++i) feat[10 + i] = x_t[(size_t)tgt * 5 + i];
        // edge_attr row: 40 B, 8B-aligned -> float2 x5 (streamed, coalesced-ish)
        const float2* ea2 = reinterpret_cast<const float2*>(edge_attr + (size_t)e * 10);
        #pragma unroll
        for (int i = 0; i < 5; ++i) {
            float2 v = ea2[i];
            feat[15 + 2 * i] = v.x;
            feat[16 + 2 * i] = v.y;
        }
        // u row from LDS
        #pragma unroll
        for (int i = 0; i < 10; ++i) feat[25 + i] = su[b * 11 + i];

        // h = leaky_relu(feat @ W1 + b1, 0.1)
        float h[5];
        #pragma unroll
        for (int j = 0; j < 5; ++j) {
            float acc = sb1[j];
            #pragma unroll
            for (int k = 0; k < 35; ++k) acc = fmaf(feat[k], sW1[k * 5 + j], acc);
            h[j] = (acc > 0.0f) ? acc : 0.1f * acc;
        }
        // out = h @ W2 + b2  -> stage to LDS (stride 5 coprime w/ 32: conflict-free)
        #pragma unroll
        for (int j = 0; j < 5; ++j) {
            float acc = sb2[j];
            #pragma unroll
            for (int i = 0; i < 5; ++i) acc = fmaf(h[i], sW2[i * 5 + j], acc);
            sout[t * 5 + j] = acc;
        }
    }
    __syncthreads();

    // coalesced block store: contiguous floats, stride-1 per instruction
    const size_t base  = (size_t)blockIdx.x * THREADS * 5;
    const int nvalid   = min(THREADS, E - blockIdx.x * THREADS);
    const int nfloats  = nvalid * 5;
    for (int i = t; i < nfloats; i += THREADS) out[base + i] = sout[i];
}

extern "C" void kernel_launch(void* const* d_in, const int* in_sizes, int n_in,
                              void* d_out, int out_size, void* d_ws, size_t ws_size,
                              hipStream_t stream)
{
    const float* x_s       = (const float*)d_in[0];
    const float* x_t       = (const float*)d_in[1];
    const int*   edge_idx  = (const int*)  d_in[2];
    const float* edge_attr = (const float*)d_in[3];
    const float* u         = (const float*)d_in[4];
    const int*   batch_e   = (const int*)  d_in[5];
    const float* W1        = (const float*)d_in[6];
    const float* b1        = (const float*)d_in[7];
    const float* W2        = (const float*)d_in[8];
    const float* b2        = (const float*)d_in[9];
    float*       out       = (float*)d_out;

    const int E = in_sizes[5];  // batch_e has E elements

    const int grid = (E + THREADS - 1) / THREADS;
    edge_model_kernel<<<grid, THREADS, 0, stream>>>(
        x_s, x_t, edge_idx, edge_attr, u, batch_e, W1, b1, W2, b2, out, E);
}